// Round 1
// baseline (416.972 us; speedup 1.0000x reference)
//
#include <hip/hip_runtime.h>

#define NT 32768
#define DM 1024
#define NTOT (NT + 128)          // 32896 = 257 * 128 ; 128-row gap separates experts
#define NKT (DM / 64)            // 16 K-steps of BK=64

typedef __bf16 bf16x8 __attribute__((ext_vector_type(8)));
typedef float f32x4 __attribute__((ext_vector_type(4)));

// async global->LDS, 16B per lane; LDS dest is wave-uniform base + lane*16
#define GLD16(g, l)                                                            \
  __builtin_amdgcn_global_load_lds(                                            \
      (const __attribute__((address_space(1))) void*)(g),                      \
      (__attribute__((address_space(3))) void*)(l), 16, 0, 0)

__device__ __forceinline__ unsigned short f2bf(float f) {
  unsigned u = __float_as_uint(f);
  u += 0x7fffu + ((u >> 16) & 1u);   // RNE
  return (unsigned short)(u >> 16);
}

// ------- weight convert+transpose: Wt[e][n][k] = bf16(W_e[k][n]); both experts via z -------
__global__ void wt_k(const float* __restrict__ W1, const float* __restrict__ W2,
                     unsigned short* __restrict__ Wt) {
  const float* __restrict__ W = blockIdx.z ? W2 : W1;
  unsigned short* __restrict__ dst = Wt + (size_t)blockIdx.z * DM * DM;
  __shared__ float tile[32][33];
  int tx = threadIdx.x, ty = threadIdx.y;           // 32 x 8
  int n0 = blockIdx.x * 32, k0 = blockIdx.y * 32;
#pragma unroll
  for (int i = 0; i < 32; i += 8)
    tile[ty + i][tx] = W[(size_t)(k0 + ty + i) * DM + n0 + tx];
  __syncthreads();
#pragma unroll
  for (int i = 0; i < 32; i += 8)
    dst[(size_t)(n0 + ty + i) * DM + k0 + tx] = f2bf(tile[tx][ty + i]);
}

// ------- routing only: ballot-rank slot assignment, 2 atomics/wave, NO row copy -------
// expert0 fills [0, n0) front; expert1 fills from NTOT-1 downward.
// gap slots [n0, n0+128) never written; gemm guards them.
__global__ __launch_bounds__(64) void route_k(const int* __restrict__ route,
                                              int* __restrict__ idx,
                                              int* __restrict__ counters) {
  const int lane = threadIdx.x;
  const int token = blockIdx.x * 64 + lane;
  int r = route[token];
  unsigned long long m0 = __ballot(r == 0);
  unsigned long long lt = (1ULL << lane) - 1ULL;
  int rank0 = __popcll(m0 & lt);
  int rank1 = lane - rank0;
  int cnt0 = __popcll(m0);
  int base0 = 0, base1 = 0;
  if (lane == 0) {
    base0 = atomicAdd(&counters[0], cnt0);
    base1 = atomicAdd(&counters[1], 64 - cnt0);
  }
  base0 = __shfl(base0, 0, 64);
  base1 = __shfl(base1, 0, 64);
  int slot = (r == 0) ? (base0 + rank0) : (NTOT - 1 - (base1 + rank1));
  idx[slot] = token;
}

// ------- fused gather+convert grouped GEMM: 128x128 tile, BK=64, 2-phase dbuf -------
// A: gathered from x (fp32) via idx, converted to bf16 in regs, ds_write'd swizzled.
// B: global_load_lds from pre-swizzled global offsets (bf16 Wt).
// LDS XOR-swizzle: 16B chunk c of row r lives at LDS chunk r*8 + (c^(r&7)).
// Pipeline per K-step: {issue A-gather(t+1) + GLD B(t+1)} ; MFMA(t) ; ds_write A(t+1) ;
// one __syncthreads (implicit vmcnt0+lgkmcnt0 drain) -> race-free single barrier.
__global__ __launch_bounds__(256, 2) void gemm_k(
    const float* __restrict__ x,              // [NT][DM] fp32
    const unsigned short* __restrict__ Wt,    // [2][DM][DM] bf16, Wt[n][k]
    const float* __restrict__ b1, const float* __restrict__ b2,
    const int* __restrict__ idx, const int* __restrict__ counters,
    float* __restrict__ out) {
  __shared__ unsigned short As[2][128 * 64];  // swizzled [row][k-chunk], dbuf
  __shared__ unsigned short Bs[2][128 * 64];

  const int t = threadIdx.x;
  const int lane = t & 63, wave = t >> 6;

  // XCD-aware bijective swizzle: 2056 blocks = 8 XCDs x 257; put the 8 col-tiles
  // of each 128-row A-panel on the SAME XCD (consecutive logical ids per XCD).
  const int lin = blockIdx.y * 8 + blockIdx.x;       // dispatch order, x fastest
  const int L = (lin & 7) * 257 + (lin >> 3);        // bijective since 2056 % 8 == 0
  const int row0 = (L >> 3) * 128;
  const int col0 = (L & 7) * 128;

  const int n0 = counters[0];
  const int expert = (row0 < n0) ? 0 : 1;   // 128-gap => tiles never mix experts
  const unsigned short* Wte = Wt + (size_t)expert * DM * DM;
  const float* bias = expert ? b2 : b1;

  const int wr = (wave >> 1) * 64;
  const int wc = (wave & 1) * 64;
  const int lr = lane & 15;

  // per-thread A gather setup: 8 rows (p*16 + t>>4), 16B-fp32 chunk (t&15)
  const int rsub = t >> 4;
  const int c16 = t & 15;
  const float* rowp[8];
#pragma unroll
  for (int p = 0; p < 8; ++p) {
    int gr = row0 + p * 16 + rsub;
    int tok = idx[gr];
    if (gr >= n0 && gr < n0 + 128) tok = 0;   // gap rows: valid dummy, discarded later
    rowp[p] = x + (size_t)tok * DM;
  }

  float4 a[8];
  f32x4 acc[4][4] = {};

#define LOADA(k0)                                                              \
  _Pragma("unroll") for (int p = 0; p < 8; ++p)                                \
      a[p] = *(const float4*)(rowp[p] + (k0) + c16 * 4);

#define WRITEA(bufw)                                                           \
  _Pragma("unroll") for (int p = 0; p < 8; ++p) {                              \
    int r = p * 16 + rsub;                                                     \
    int off = (r * 8 + ((c16 >> 1) ^ (r & 7))) * 16 + (c16 & 1) * 8;           \
    union { unsigned short h[4]; ushort4 u4; } pk;                             \
    pk.h[0] = f2bf(a[p].x); pk.h[1] = f2bf(a[p].y);                            \
    pk.h[2] = f2bf(a[p].z); pk.h[3] = f2bf(a[p].w);                            \
    *(ushort4*)((char*)&As[bufw][0] + off) = pk.u4;                            \
  }

#define STAGEB(k0, bufw)                                                       \
  _Pragma("unroll") for (int p = 0; p < 4; ++p) {                              \
    int q = p * 256 + t;                                                       \
    int r = q >> 3;                                                            \
    int c = ((q & 7) ^ (r & 7)) * 8;                                           \
    GLD16(Wte + (size_t)(col0 + r) * DM + (k0) + c, &Bs[bufw][q * 8]);         \
  }

  // prologue: stage tile 0
  LOADA(0);
  STAGEB(0, 0);
  WRITEA(0);
  __syncthreads();

  for (int kt = 0; kt < NKT; ++kt) {
    const int buf = kt & 1;
    if (kt < NKT - 1) {        // issue-early: next tile's loads overlap MFMAs
      LOADA((kt + 1) * 64);
      STAGEB((kt + 1) * 64, buf ^ 1);
    }
#pragma unroll
    for (int s = 0; s < 2; ++s) {
      const int cb = s * 4 + (lane >> 4);   // wanted 16B chunk within the row
      bf16x8 af[4], bfr[4];
#pragma unroll
      for (int i = 0; i < 4; ++i) {
        int r = wr + i * 16 + lr;
        af[i] = *(const bf16x8*)&As[buf][(r * 8 + (cb ^ (r & 7))) * 8];
      }
#pragma unroll
      for (int j = 0; j < 4; ++j) {
        int r = wc + j * 16 + lr;
        bfr[j] = *(const bf16x8*)&Bs[buf][(r * 8 + (cb ^ (r & 7))) * 8];
      }
#pragma unroll
      for (int i = 0; i < 4; ++i)
#pragma unroll
        for (int j = 0; j < 4; ++j)
          acc[i][j] = __builtin_amdgcn_mfma_f32_16x16x32_bf16(af[i], bfr[j], acc[i][j], 0, 0, 0);
    }
    if (kt < NKT - 1) WRITEA(buf ^ 1);   // write-late: after compute, before barrier
    __syncthreads();                     // drains vmcnt (B lds) + lgkm (A writes)
  }

  // epilogue: scatter rows to original token positions, add bias (fp32).
  // gap rows [n0, n0+128) are discarded (their idx was never written).
#pragma unroll
  for (int i = 0; i < 4; ++i) {
#pragma unroll
    for (int reg = 0; reg < 4; ++reg) {
      int gr = row0 + wr + i * 16 + (lane >> 4) * 4 + reg;
      if (gr < n0 || gr >= n0 + 128) {
        int dest = idx[gr];
#pragma unroll
        for (int j = 0; j < 4; ++j) {
          int gc = col0 + wc + j * 16 + (lane & 15);
          out[(size_t)dest * DM + gc] = acc[i][j][reg] + bias[gc];
        }
      }
    }
  }
#undef LOADA
#undef WRITEA
#undef STAGEB
}

extern "C" void kernel_launch(void* const* d_in, const int* in_sizes, int n_in,
                              void* d_out, int out_size, void* d_ws, size_t ws_size,
                              hipStream_t stream) {
  const float* x   = (const float*)d_in[0];
  const float* W1  = (const float*)d_in[1];
  const float* b1  = (const float*)d_in[2];
  const float* W2  = (const float*)d_in[3];
  const float* b2  = (const float*)d_in[4];
  const int*   route = (const int*)d_in[5];
  float* out = (float*)d_out;

  char* ws = (char*)d_ws;
  unsigned short* Wt = (unsigned short*)ws;            // 2*DM*DM bf16 = 4 MB
  size_t off = (size_t)2 * DM * DM * 2;
  int* idx = (int*)(ws + off);                         // NTOT ints
  int* counters = idx + NTOT;                          // 2 ints

  hipMemsetAsync(counters, 0, 2 * sizeof(int), stream);
  route_k<<<NT / 64, 64, 0, stream>>>(route, idx, counters);
  wt_k<<<dim3(DM / 32, DM / 32, 2), dim3(32, 8), 0, stream>>>(W1, W2, Wt);
  gemm_k<<<dim3(8, NTOT / 128), 256, 0, stream>>>(x, Wt, b1, b2, idx, counters, out);
}

// Round 2
// 356.966 us; speedup vs baseline: 1.1681x; 1.1681x over previous
//
#include <hip/hip_runtime.h>

#define NT 32768
#define DM 1024
#define NTOT (NT + 128)          // 32896 = 257 * 128 ; 128-row gap separates experts
#define NKT (DM / 64)            // 16 K-steps of BK=64

typedef __bf16 bf16x8 __attribute__((ext_vector_type(8)));
typedef float f32x4 __attribute__((ext_vector_type(4)));

// async global->LDS, 16B per lane; LDS dest is wave-uniform base + lane*16
#define GLD16(g, l)                                                            \
  __builtin_amdgcn_global_load_lds(                                            \
      (const __attribute__((address_space(1))) void*)(g),                      \
      (__attribute__((address_space(3))) void*)(l), 16, 0, 0)

__device__ __forceinline__ unsigned short f2bf(float f) {
  unsigned u = __float_as_uint(f);
  u += 0x7fffu + ((u >> 16) & 1u);   // RNE
  return (unsigned short)(u >> 16);
}

// ------- weight convert+transpose: Wt[e][n][k] = bf16(W_e[k][n]); both experts via z -------
__global__ void wt_k(const float* __restrict__ W1, const float* __restrict__ W2,
                     unsigned short* __restrict__ Wt) {
  const float* __restrict__ W = blockIdx.z ? W2 : W1;
  unsigned short* __restrict__ dst = Wt + (size_t)blockIdx.z * DM * DM;
  __shared__ float tile[32][33];
  int tx = threadIdx.x, ty = threadIdx.y;           // 32 x 8
  int n0 = blockIdx.x * 32, k0 = blockIdx.y * 32;
#pragma unroll
  for (int i = 0; i < 32; i += 8)
    tile[ty + i][tx] = W[(size_t)(k0 + ty + i) * DM + n0 + tx];
  __syncthreads();
#pragma unroll
  for (int i = 0; i < 32; i += 8)
    dst[(size_t)(n0 + ty + i) * DM + k0 + tx] = f2bf(tile[tx][ty + i]);
}

// ------- routing only: ballot-rank slot assignment, 2 atomics/wave, NO row copy -------
__global__ __launch_bounds__(64) void route_k(const int* __restrict__ route,
                                              int* __restrict__ idx,
                                              int* __restrict__ counters) {
  const int lane = threadIdx.x;
  const int token = blockIdx.x * 64 + lane;
  int r = route[token];
  unsigned long long m0 = __ballot(r == 0);
  unsigned long long lt = (1ULL << lane) - 1ULL;
  int rank0 = __popcll(m0 & lt);
  int rank1 = lane - rank0;
  int cnt0 = __popcll(m0);
  int base0 = 0, base1 = 0;
  if (lane == 0) {
    base0 = atomicAdd(&counters[0], cnt0);
    base1 = atomicAdd(&counters[1], 64 - cnt0);
  }
  base0 = __shfl(base0, 0, 64);
  base1 = __shfl(base1, 0, 64);
  int slot = (r == 0) ? (base0 + rank0) : (NTOT - 1 - (base1 + rank1));
  idx[slot] = token;
}

// ------- fused gather+convert grouped GEMM: 128x128 tile, BK=64 -------
// A: gathered from x (fp32) via idx -> regs (a[] IS the A double-buffer),
//    converted to bf16, ds_write'd swizzled into single-buffer As (16 KiB).
// B: global_load_lds into double-buffered Bs (32 KiB). Total LDS 48 KiB -> 3 blk/CU.
// Per K-step: WRITEA(kt); bar1 (drains only ds_writes; B(kt) landed under prior
// MFMA); issue LOADA/STAGEB(kt+1); MFMA(kt); bar2 (its blanket vmcnt(0) drain is
// covered by the MFMA phase) -> both load latencies hidden with plain barriers.
__global__ __launch_bounds__(256, 3) void gemm_k(
    const float* __restrict__ x,              // [NT][DM] fp32
    const unsigned short* __restrict__ Wt,    // [2][DM][DM] bf16, Wt[n][k]
    const float* __restrict__ b1, const float* __restrict__ b2,
    const int* __restrict__ idx, const int* __restrict__ counters,
    float* __restrict__ out) {
  __shared__ unsigned short As[128 * 64];     // swizzled [row][k-chunk], single buf
  __shared__ unsigned short Bs[2][128 * 64];  // double buf

  const int t = threadIdx.x;
  const int lane = t & 63, wave = t >> 6;

  // XCD-aware bijective swizzle: 2056 blocks = 8 XCDs x 257; the 8 col-tiles of
  // each 128-row A-panel get consecutive logical ids on the SAME XCD.
  const int lin = blockIdx.y * 8 + blockIdx.x;       // dispatch order, x fastest
  const int L = (lin & 7) * 257 + (lin >> 3);        // bijective since 2056 % 8 == 0
  const int row0 = (L >> 3) * 128;
  const int col0 = (L & 7) * 128;

  const int n0 = counters[0];
  const int expert = (row0 < n0) ? 0 : 1;   // 128-gap => tiles never mix experts
  const unsigned short* Wte = Wt + (size_t)expert * DM * DM;
  const float* bias = expert ? b2 : b1;

  const int wr = (wave >> 1) * 64;
  const int wc = (wave & 1) * 64;
  const int lr = lane & 15;

  // per-thread A gather setup: 8 rows (p*16 + t>>4), 16B-fp32 chunk (t&15)
  const int rsub = t >> 4;
  const int c16 = t & 15;
  const float* rowp[8];
#pragma unroll
  for (int p = 0; p < 8; ++p) {
    int gr = row0 + p * 16 + rsub;
    int tok = idx[gr];
    if (gr >= n0 && gr < n0 + 128) tok = 0;   // gap rows: valid dummy, discarded later
    rowp[p] = x + (size_t)tok * DM;
  }

  float4 a[8];
  f32x4 acc[4][4] = {};

#define LOADA(k0)                                                              \
  _Pragma("unroll") for (int p = 0; p < 8; ++p)                                \
      a[p] = *(const float4*)(rowp[p] + (k0) + c16 * 4);

// write a[] (fp32) as bf16 into swizzled As: chunk c of row r at chunk r*8+(c^(r&7))
#define WRITEA()                                                               \
  _Pragma("unroll") for (int p = 0; p < 8; ++p) {                              \
    int r = p * 16 + rsub;                                                     \
    int off = (r * 8 + ((c16 >> 1) ^ (r & 7))) * 16 + (c16 & 1) * 8;           \
    union { unsigned short h[4]; ushort4 u4; } pk;                             \
    pk.h[0] = f2bf(a[p].x); pk.h[1] = f2bf(a[p].y);                            \
    pk.h[2] = f2bf(a[p].z); pk.h[3] = f2bf(a[p].w);                            \
    *(ushort4*)((char*)&As[0] + off) = pk.u4;                                  \
  }

#define STAGEB(k0, bufw)                                                       \
  _Pragma("unroll") for (int p = 0; p < 4; ++p) {                              \
    int q = p * 256 + t;                                                       \
    int r = q >> 3;                                                            \
    int c = ((q & 7) ^ (r & 7)) * 8;                                           \
    GLD16(Wte + (size_t)(col0 + r) * DM + (k0) + c, &Bs[bufw][q * 8]);         \
  }

  // prologue: A(0) into regs, B(0) into Bs[0]
  LOADA(0);
  STAGEB(0, 0);

  for (int kt = 0; kt < NKT; ++kt) {
    const int buf = kt & 1;
    WRITEA();                  // consumes a[] = A(kt)
    __syncthreads();           // As(kt) visible; B(kt) drained (landed under prior MFMA)
    if (kt < NKT - 1) {
      LOADA((kt + 1) * 64);            // A(kt+1) -> regs, hidden under MFMA below
      STAGEB((kt + 1) * 64, buf ^ 1);  // B(kt+1) -> other LDS buf, hidden too
    }
#pragma unroll
    for (int s = 0; s < 2; ++s) {
      const int cb = s * 4 + (lane >> 4);   // wanted 16B chunk within the row
      bf16x8 af[4], bfr[4];
#pragma unroll
      for (int i = 0; i < 4; ++i) {
        int r = wr + i * 16 + lr;
        af[i] = *(const bf16x8*)&As[(r * 8 + (cb ^ (r & 7))) * 8];
      }
#pragma unroll
      for (int j = 0; j < 4; ++j) {
        int r = wc + j * 16 + lr;
        bfr[j] = *(const bf16x8*)&Bs[buf][(r * 8 + (cb ^ (r & 7))) * 8];
      }
#pragma unroll
      for (int i = 0; i < 4; ++i)
#pragma unroll
        for (int j = 0; j < 4; ++j)
          acc[i][j] = __builtin_amdgcn_mfma_f32_16x16x32_bf16(af[i], bfr[j], acc[i][j], 0, 0, 0);
    }
    __syncthreads();           // vmcnt(0) drain covered by MFMA phase; As free to overwrite
  }

  // epilogue: scatter rows to original token positions, add bias (fp32).
#pragma unroll
  for (int i = 0; i < 4; ++i) {
#pragma unroll
    for (int reg = 0; reg < 4; ++reg) {
      int gr = row0 + wr + i * 16 + (lane >> 4) * 4 + reg;
      if (gr < n0 || gr >= n0 + 128) {
        int dest = idx[gr];
#pragma unroll
        for (int j = 0; j < 4; ++j) {
          int gc = col0 + wc + j * 16 + (lane & 15);
          out[(size_t)dest * DM + gc] = acc[i][j][reg] + bias[gc];
        }
      }
    }
  }
#undef LOADA
#undef WRITEA
#undef STAGEB
}

extern "C" void kernel_launch(void* const* d_in, const int* in_sizes, int n_in,
                              void* d_out, int out_size, void* d_ws, size_t ws_size,
                              hipStream_t stream) {
  const float* x   = (const float*)d_in[0];
  const float* W1  = (const float*)d_in[1];
  const float* b1  = (const float*)d_in[2];
  const float* W2  = (const float*)d_in[3];
  const float* b2  = (const float*)d_in[4];
  const int*   route = (const int*)d_in[5];
  float* out = (float*)d_out;

  char* ws = (char*)d_ws;
  unsigned short* Wt = (unsigned short*)ws;            // 2*DM*DM bf16 = 4 MB
  size_t off = (size_t)2 * DM * DM * 2;
  int* idx = (int*)(ws + off);                         // NTOT ints
  int* counters = idx + NTOT;                          // 2 ints

  hipMemsetAsync(counters, 0, 2 * sizeof(int), stream);
  route_k<<<NT / 64, 64, 0, stream>>>(route, idx, counters);
  wt_k<<<dim3(DM / 32, DM / 32, 2), dim3(32, 8), 0, stream>>>(W1, W2, Wt);
  gemm_k<<<dim3(8, NTOT / 128), 256, 0, stream>>>(x, Wt, b1, b2, idx, counters, out);
}